// Round 1
// baseline (166.622 us; speedup 1.0000x reference)
//
#include <hip/hip_runtime.h>
#include <math.h>

#define BB 256
#define TT 512
#define KK 20
#define START_TAG 18
#define STOP_TAG 19
#define NST 400  // KK*KK

__device__ __forceinline__ float fexp2(float x) {
    float r;
    asm("v_exp_f32 %0, %1" : "=v"(r) : "v"(x));
    return r;
}
__device__ __forceinline__ float flog2(float x) {
    float r;
    asm("v_log_f32 %0, %1" : "=v"(r) : "v"(x));
    return r;
}

// Forward algorithm: one block (1 wave) per batch element.
// Lane i (<20) owns output tag i; alpha kept in LDS in base-2 scale.
__global__ __launch_bounds__(64, 1) void fwd_kernel(
    const float* __restrict__ feats, const float* __restrict__ trans,
    const int* __restrict__ targets, const int* __restrict__ lengths,
    float* __restrict__ partialA)
{
    constexpr float LOG2E = 1.4426950408889634f;
    constexpr float LN2   = 0.6931471805599453f;

    const int b    = blockIdx.x;
    const int lane = threadIdx.x;
    const int len  = lengths[b];
    const float* fb = feats + (size_t)b * TT * NST;

    __shared__ __align__(16) float alpha[KK];
    __shared__ __align__(16) float xs[KK];

    const bool act = lane < KK;
    const int  li  = act ? lane : 0;  // clamp so idle lanes stay in-bounds

    if (act) alpha[lane] = fb[lane * KK + START_TAG] * LOG2E;
    __syncthreads();

    // depth-4 register pipeline of feature rows: buf[q] = f[b,t,li,4q..4q+3]
    float4 b0[5], b1[5], b2[5], b3[5];

    auto LOAD = [&](float4* dst, int t) {
        int tc = (t < len) ? t : (len - 1);  // clamp: redundant but in-bounds
        const float4* p = (const float4*)(fb + (size_t)tc * NST + li * KK);
        dst[0] = p[0]; dst[1] = p[1]; dst[2] = p[2]; dst[3] = p[3]; dst[4] = p[4];
    };

    auto STEP = [&](const float4* bufv) {
        // broadcast-read alpha (base-2)
        const float4* ap = (const float4*)alpha;
        float a[KK];
        #pragma unroll
        for (int q = 0; q < 5; ++q) {
            float4 av = ap[q];
            a[4*q+0] = av.x; a[4*q+1] = av.y; a[4*q+2] = av.z; a[4*q+3] = av.w;
        }
        float v[KK];
        #pragma unroll
        for (int q = 0; q < 5; ++q) {
            v[4*q+0] = bufv[q].x * LOG2E + a[4*q+0];
            v[4*q+1] = bufv[q].y * LOG2E + a[4*q+1];
            v[4*q+2] = bufv[q].z * LOG2E + a[4*q+2];
            v[4*q+3] = bufv[q].w * LOG2E + a[4*q+3];
        }
        float m = v[0];
        #pragma unroll
        for (int j = 1; j < KK; ++j) m = fmaxf(m, v[j]);
        float s = 0.f;
        #pragma unroll
        for (int j = 0; j < KK; ++j) s += fexp2(v[j] - m);
        float na = m + flog2(s);
        __syncthreads();                 // everyone done reading old alpha
        if (act) alpha[lane] = na;
        __syncthreads();
    };

    LOAD(b0, 1); LOAD(b1, 2); LOAD(b2, 3); LOAD(b3, 4);

    int t = 1;
    while (t < len) {
        STEP(b0); LOAD(b0, t + 4); ++t; if (t >= len) break;
        STEP(b1); LOAD(b1, t + 4); ++t; if (t >= len) break;
        STEP(b2); LOAD(b2, t + 4); ++t; if (t >= len) break;
        STEP(b3); LOAD(b3, t + 4); ++t;
    }

    // final LSE_i(alpha_i + trans[STOP, i]) in nats, minus trans[STOP, last_tag]
    if (act) xs[lane] = alpha[lane] + trans[STOP_TAG * KK + lane] * LOG2E;
    __syncthreads();
    if (lane == 0) {
        float m = xs[0];
        for (int j = 1; j < KK; ++j) m = fmaxf(m, xs[j]);
        float s = 0.f;
        for (int j = 0; j < KK; ++j) s += fexp2(xs[j] - m);
        float lse = LN2 * (m + flog2(s));
        int last_tag = targets[b * TT + (len - 1)];
        partialA[b] = lse - trans[STOP_TAG * KK + last_tag];
    }
}

// Gold path score gather: one thread per (b, t)
__global__ __launch_bounds__(256) void gold_kernel(
    const float* __restrict__ feats, const int* __restrict__ targets,
    const int* __restrict__ lengths, float* __restrict__ partialG)
{
    const int b  = blockIdx.x;
    const int tt = blockIdx.y * 256 + threadIdx.x;
    const int len = lengths[b];

    float val = 0.f;
    if (tt < len) {
        int tgt  = targets[b * TT + tt];
        int prev = (tt > 0) ? targets[b * TT + tt - 1] : START_TAG;
        val = feats[((size_t)b * TT + tt) * NST + tgt * KK + prev];
    }
    #pragma unroll
    for (int off = 32; off > 0; off >>= 1) val += __shfl_down(val, off);

    __shared__ float wsum[4];
    if ((threadIdx.x & 63) == 0) wsum[threadIdx.x >> 6] = val;
    __syncthreads();
    if (threadIdx.x == 0)
        partialG[b * gridDim.y + blockIdx.y] = wsum[0] + wsum[1] + wsum[2] + wsum[3];
}

// out = sum(partialA) - sum(partialG); deterministic single-block reduce
__global__ __launch_bounds__(256) void final_kernel(
    const float* __restrict__ partialA, const float* __restrict__ partialG,
    float* __restrict__ out)
{
    int tid = threadIdx.x;
    float v = partialA[tid] - partialG[tid] - partialG[tid + 256];
    #pragma unroll
    for (int off = 32; off > 0; off >>= 1) v += __shfl_down(v, off);

    __shared__ float wsum[4];
    if ((tid & 63) == 0) wsum[tid >> 6] = v;
    __syncthreads();
    if (tid == 0) out[0] = wsum[0] + wsum[1] + wsum[2] + wsum[3];
}

extern "C" void kernel_launch(void* const* d_in, const int* in_sizes, int n_in,
                              void* d_out, int out_size, void* d_ws, size_t ws_size,
                              hipStream_t stream) {
    const float* feats   = (const float*)d_in[0];
    const float* trans   = (const float*)d_in[1];
    const int*   targets = (const int*)d_in[2];
    const int*   lengths = (const int*)d_in[3];

    float* partialA = (float*)d_ws;        // 256 floats
    float* partialG = partialA + 256;      // 512 floats (B * 2 chunks)

    fwd_kernel<<<dim3(BB), dim3(64), 0, stream>>>(feats, trans, targets, lengths, partialA);
    gold_kernel<<<dim3(BB, 2), dim3(256), 0, stream>>>(feats, targets, lengths, partialG);
    final_kernel<<<dim3(1), dim3(256), 0, stream>>>(partialA, partialG, (float*)d_out);
}